// Round 4
// baseline (408.392 us; speedup 1.0000x reference)
//
#include <hip/hip_runtime.h>
#include <hip/hip_bf16.h>
#include <stdint.h>

typedef unsigned short u16;
typedef unsigned int u32;
typedef short bf16x8 __attribute__((ext_vector_type(8)));
typedef float f32x4 __attribute__((ext_vector_type(4)));
typedef float f32x16 __attribute__((ext_vector_type(16)));
typedef unsigned short u16x4 __attribute__((ext_vector_type(4)));
typedef int i32x4 __attribute__((ext_vector_type(4)));

#define NSEQ   3072
#define QSCALE 0.158113883008418966599446f

// ws layout (bytes)
#define OFF_XB   ((size_t)0)          // x bf16 [6144][320]
#define OFF_CB   ((size_t)3932160)    // context bf16 [6144][320]
#define OFF_WT   ((size_t)7864320)    // 4x Wt bf16 [320][320] q,k,v,o
#define OFF_QG   ((size_t)8683520)    // Q bf16 [6144][320] (scale folded)
#define OFF_KG   ((size_t)12615680)   // K bf16 [6144][320]
#define OFF_VT   ((size_t)16547840)   // V^T bf16 [16][48][3072] (40..46 zero, 47 ones)
#define OFF_OB   ((size_t)21266432)   // attn out bf16 [6144][320]
#define OFF_M1   ((size_t)25198592)   // m1i bf16 [2][3072]: 1.0 if masked else 0
#define OFF_M2   ((size_t)25210880)   // m2n bf16 [2][3072]: -1e30 if masked else 0

__device__ __forceinline__ u16 f2bf(float x) {
  __hip_bfloat16 h = __float2bfloat16(x);
  return __builtin_bit_cast(unsigned short, h);
}
__device__ __forceinline__ u32 pk(float lo, float hif) {
  return (u32)f2bf(lo) | ((u32)f2bf(hif) << 16);
}
__device__ __forceinline__ void lds_cp16(const void* g, void* l) {
  __builtin_amdgcn_global_load_lds((const __attribute__((address_space(1))) void*)g,
                                   (__attribute__((address_space(3))) void*)l, 16, 0, 0);
}

// ---------------------------------------------------------------- prep
__global__ void prep_kernel(const float* __restrict__ x, const float* __restrict__ ctx,
                            const float* __restrict__ mask1, const float* __restrict__ mask2,
                            const float* __restrict__ Wq, const float* __restrict__ Wk,
                            const float* __restrict__ Wv, const float* __restrict__ Wo,
                            unsigned char* __restrict__ ws) {
  u16* xb = (u16*)(ws + OFF_XB);
  u16* cb = (u16*)(ws + OFF_CB);
  const int T0 = 491520;            // x float4 tasks
  const int T1 = T0 + 491520;       // ctx
  const int T2 = T1 + 102400;       // W transpose (4 * 25600)
  const int T3 = T2 + 1536;         // m1i (4 u16/task)
  const int T4 = T3 + 1536;         // m2n
  const int T5 = T4 + 49152;        // V^T pad rows (8 bf16/task)
  const int stride = gridDim.x * blockDim.x;
  for (int i = blockIdx.x * blockDim.x + threadIdx.x; i < T5; i += stride) {
    if (i < T1) {
      const float* src = (i < T0) ? x : ctx;
      u16* dst = (i < T0) ? xb : cb;
      int j = (i < T0) ? i : i - T0;
      float4 v = ((const float4*)src)[j];
      u16x4 o;
      o[0] = f2bf(v.x); o[1] = f2bf(v.y); o[2] = f2bf(v.z); o[3] = f2bf(v.w);
      *(u16x4*)(dst + (size_t)j * 4) = o;
    } else if (i < T2) {
      int j = i - T1;
      int m = j / 25600, rr = j % 25600;
      const float* W = (m == 0) ? Wq : (m == 1) ? Wk : (m == 2) ? Wv : Wo;
      u16* Wt = (u16*)(ws + OFF_WT + (size_t)m * 204800);
      int base = rr * 4, d = base / 320, k = base % 320;
      u16x4 o;
#pragma unroll
      for (int t = 0; t < 4; ++t) o[t] = f2bf(W[(size_t)(k + t) * 320 + d]);
      *(u16x4*)(Wt + (size_t)d * 320 + k) = o;
    } else if (i < T4) {
      bool isM1 = i < T3;
      int j = isM1 ? (i - T2) : (i - T3);
      const float* msk = isM1 ? mask1 : mask2;
      u16* dst = (u16*)(ws + (isM1 ? OFF_M1 : OFF_M2));
      int base = j * 4, b = base / 3072, r0 = base % 3072;
      u16x4 o;
#pragma unroll
      for (int t = 0; t < 4; ++t) {
        int rr = r0 + t, ih = rr / 48, iw = rr % 48;
        float mv = msk[(size_t)b * 196608 + ih * 3072 + iw * 8];
        bool on = mv >= 0.5f;
        o[t] = isM1 ? f2bf(on ? 1.0f : 0.0f) : f2bf(on ? -1e30f : 0.0f);
      }
      *(u16x4*)(dst + base) = o;
    } else {
      int j = i - T4;
      int idx8 = j * 8;
      int bh = idx8 / 24576, rem = idx8 % 24576;
      int pr = rem / 3072, c = rem % 3072;
      u16* Vt = (u16*)(ws + OFF_VT);
      u32 fill = (pr == 7) ? 0x3F803F80u : 0u;  // row 47 = ones (softmax denom via MFMA)
      i32x4 z = {(int)fill, (int)fill, (int)fill, (int)fill};
      *(i32x4*)(Vt + (size_t)(bh * 48 + 40 + pr) * 3072 + c) = z;
    }
  }
}

// ---------------------------------------------------------------- GEMMs (merged)
// mode 0: Q = xb @ WqT^T (scaled)   mode 1: K = cb @ WkT^T
// mode 2: V^T = WvT @ cb^T          mode 3: out = Ob @ WoT^T + bo
__global__ __launch_bounds__(256) void gemm_all(unsigned char* __restrict__ ws,
                                                const float* __restrict__ bo,
                                                float* __restrict__ outf, int phase) {
  const u16* xb = (const u16*)(ws + OFF_XB);
  const u16* cb = (const u16*)(ws + OFF_CB);
  const int mode = phase ? 3 : (int)blockIdx.y;
  const u16* Ap; const u16* Bp;
  int bx = blockIdx.x;
  int mt, nt;
  if (mode == 0)      { Ap = xb; Bp = (const u16*)(ws + OFF_WT);            mt = bx / 5; nt = bx % 5; }
  else if (mode == 1) { Ap = cb; Bp = (const u16*)(ws + OFF_WT + 204800);   mt = bx / 5; nt = bx % 5; }
  else if (mode == 2) { Ap = (const u16*)(ws + OFF_WT + 2 * 204800); Bp = cb; mt = bx % 5; nt = bx / 5; }
  else                { Ap = (const u16*)(ws + OFF_OB); Bp = (const u16*)(ws + OFF_WT + 3 * 204800); mt = bx / 5; nt = bx % 5; }
  const int m0 = mt * 64, n0 = nt * 64;

  __shared__ u16 Als[64 * 32];
  __shared__ u16 Bls[64 * 32];

  const int tid = threadIdx.x;
  const int lane = tid & 63, w = tid >> 6;
  const int li = lane & 15, g = lane >> 4;

  f32x4 acc[4] = {};

  const int srow = tid >> 2, sslot = tid & 3;
  const int sgch = (sslot - ((srow >> 1) & 3)) & 3;
  const u16* aSrc = Ap + (size_t)(m0 + srow) * 320 + sgch * 8;
  const u16* bSrc = Bp + (size_t)(n0 + srow) * 320 + sgch * 8;

  const int arow = w * 16 + li;
  const int aoff = arow * 32 + (((g + ((arow >> 1) & 3)) & 3) * 8);

  for (int kt = 0; kt < 10; ++kt) {
    __syncthreads();
    lds_cp16(aSrc + kt * 32, (char*)Als + tid * 16);
    lds_cp16(bSrc + kt * 32, (char*)Bls + tid * 16);
    __syncthreads();
    bf16x8 af = *(const bf16x8*)(Als + aoff);
#pragma unroll
    for (int ct = 0; ct < 4; ++ct) {
      int brow = ct * 16 + li;
      bf16x8 bv = *(const bf16x8*)(Bls + brow * 32 + (((g + ((brow >> 1) & 3)) & 3) * 8));
      acc[ct] = __builtin_amdgcn_mfma_f32_16x16x32_bf16(af, bv, acc[ct], 0, 0, 0);
    }
  }

  const int erow = w * 16 + g * 4;
  if (mode == 0 || mode == 1) {
    u16* Og = (u16*)(ws + (mode == 0 ? OFF_QG : OFF_KG));
#pragma unroll
    for (int ct = 0; ct < 4; ++ct)
#pragma unroll
      for (int r = 0; r < 4; ++r) {
        float v = acc[ct][r];
        if (mode == 0) v *= QSCALE;
        Og[(size_t)(m0 + erow + r) * 320 + n0 + ct * 16 + li] = f2bf(v);
      }
  } else if (mode == 2) {
    u16* Vt = (u16*)(ws + OFF_VT);
#pragma unroll
    for (int ct = 0; ct < 4; ++ct)
#pragma unroll
      for (int r = 0; r < 4; ++r) {
        int d = m0 + erow + r;
        int h = d / 40, dd = d % 40;
        int n = n0 + ct * 16 + li;
        int b = (n >= 3072) ? 1 : 0;
        int nin = n - b * 3072;
        int bh = b * 8 + h;
        Vt[(size_t)(bh * 48 + dd) * 3072 + nin] = f2bf(acc[ct][r]);
      }
  } else {
#pragma unroll
    for (int ct = 0; ct < 4; ++ct) {
      float bias = bo[n0 + ct * 16 + li];
#pragma unroll
      for (int r = 0; r < 4; ++r)
        outf[(size_t)(m0 + erow + r) * 320 + n0 + ct * 16 + li] = acc[ct][r] + bias;
    }
  }
}

// ---------------------------------------------------------------- attention
// Block = one (bh, qs) pair, 4 waves; wave w handles keys [w*768, w*768+768)
// (split-K is exactly additive: no online max, partial O/L just sum).
// Swapped QK^T (A=K, B=Q); mask folded into contraction pad dim; denominator
// via ones-row 47 of V^T (oacc1 col 15). Waves 1-3 dump partials to LDS,
// wave 0 reduces + normalizes + writes.
__global__ __launch_bounds__(256, 6) void attn_kernel(unsigned char* __restrict__ ws) {
  const u16* Qg  = (const u16*)(ws + OFF_QG);
  const u16* Kg  = (const u16*)(ws + OFF_KG);
  const u16* Vt  = (const u16*)(ws + OFF_VT);
  const u16* m1i = (const u16*)(ws + OFF_M1);
  const u16* m2n = (const u16*)(ws + OFF_M2);
  u16* Ob = (u16*)(ws + OFF_OB);

  __shared__ float part[3][2][16][64];   // [wave-1][acc][reg][lane]

  const int tid = threadIdx.x;
  const int w = tid >> 6;                 // wave in block, 0..3
  const int lane = tid & 63;
  const int l31 = lane & 31, hi = lane >> 5;

  // XCD-bijective swizzle: 1536 blocks = 8 XCD * 192; physical p -> logical
  // so each XCD hosts 2 consecutive bh (its L2 keeps their K/V resident).
  const int p = blockIdx.x;
  const int logical = (p & 7) * 192 + (p >> 3);
  const int bh = logical / 96, qs = logical % 96;
  const int b = bh >> 3, h = bh & 7;
  const int q0 = qs * 32;

  // Q B-fragments (col = q = l31, k-chunk = 2t + hi), chunk 5 = m1 indicator
  const u16* qrow = Qg + (size_t)(b * NSEQ + q0 + l31) * 320 + h * 40;
  bf16x8 qf0 = *(const bf16x8*)(qrow + hi * 8);
  bf16x8 qf1 = *(const bf16x8*)(qrow + 16 + hi * 8);
  bf16x8 qf2;
  {
    i32x4 real = *(const i32x4*)(qrow + 32);
    u16 m1v = m1i[b * NSEQ + q0 + l31];
    i32x4 mskv = {(int)(u32)m1v, 0, 0, 0};
    i32x4 sel = hi ? mskv : real;
    qf2 = __builtin_bit_cast(bf16x8, sel);
  }

  const int k0base = w * 768;
  const u16* kb0 = Kg + (size_t)(b * NSEQ + k0base + l31) * 320 + h * 40 + hi * 8;
  const u16* kb1 = kb0 + 32 * 320;
  const u16* vb0 = Vt + ((size_t)(bh * 48) + l31) * 3072 + k0base + hi * 8;
  const u16* vb1 = vb0 + 32 * 3072;
  const u16* m2p = m2n + b * NSEQ + k0base + l31;

  f32x16 oacc0 = {}, oacc1 = {};

#pragma unroll 2
  for (int kt = 0; kt < 12; ++kt) {
    // K A-frags (row = key = l31 (+32), k-chunk = 2t + hi)
    bf16x8 ka00 = *(const bf16x8*)(kb0);
    bf16x8 ka01 = *(const bf16x8*)(kb0 + 16);
    bf16x8 ka02 = *(const bf16x8*)(kb0 + 32);
    bf16x8 ka10 = *(const bf16x8*)(kb1);
    bf16x8 ka11 = *(const bf16x8*)(kb1 + 16);
    bf16x8 ka12 = *(const bf16x8*)(kb1 + 32);
    u16 m2v0 = m2p[0], m2v1 = m2p[32];
    // V B-frags (col = d = l31 (+32), k = ks*16 + 8*hi + e)
    bf16x8 vf00 = *(const bf16x8*)(vb0);
    bf16x8 vf01 = *(const bf16x8*)(vb0 + 16);
    bf16x8 vf02 = *(const bf16x8*)(vb0 + 32);
    bf16x8 vf03 = *(const bf16x8*)(vb0 + 48);
    bf16x8 vf10 = *(const bf16x8*)(vb1);
    bf16x8 vf11 = *(const bf16x8*)(vb1 + 16);
    bf16x8 vf12 = *(const bf16x8*)(vb1 + 32);
    bf16x8 vf13 = *(const bf16x8*)(vb1 + 48);

    // hi=1 lanes: replace chunk-5 with mask row (-1e30 if m2)
    {
      i32x4 mv0 = {(int)(u32)m2v0, 0, 0, 0};
      i32x4 mv1 = {(int)(u32)m2v1, 0, 0, 0};
      ka02 = hi ? __builtin_bit_cast(bf16x8, mv0) : ka02;
      ka12 = hi ? __builtin_bit_cast(bf16x8, mv1) : ka12;
    }

    f32x16 s0 = {}, s1 = {};
    s0 = __builtin_amdgcn_mfma_f32_32x32x16_bf16(ka00, qf0, s0, 0, 0, 0);
    s0 = __builtin_amdgcn_mfma_f32_32x32x16_bf16(ka01, qf1, s0, 0, 0, 0);
    s0 = __builtin_amdgcn_mfma_f32_32x32x16_bf16(ka02, qf2, s0, 0, 0, 0);
    s1 = __builtin_amdgcn_mfma_f32_32x32x16_bf16(ka10, qf0, s1, 0, 0, 0);
    s1 = __builtin_amdgcn_mfma_f32_32x32x16_bf16(ka11, qf1, s1, 0, 0, 0);
    s1 = __builtin_amdgcn_mfma_f32_32x32x16_bf16(ka12, qf2, s1, 0, 0, 0);

    // exp (no max subtraction: |S| bounded, masked -> exact 0) + bf16 pack
    u32 w0[4][2], w1[4][2];
#pragma unroll
    for (int t = 0; t < 4; ++t) {
      w0[t][0] = pk(__expf(s0[4 * t]),     __expf(s0[4 * t + 1]));
      w0[t][1] = pk(__expf(s0[4 * t + 2]), __expf(s0[4 * t + 3]));
      w1[t][0] = pk(__expf(s1[4 * t]),     __expf(s1[4 * t + 1]));
      w1[t][1] = pk(__expf(s1[4 * t + 2]), __expf(s1[4 * t + 3]));
    }
    // cross-half exchange (muxed so each lane sends what its partner needs)
    u32 r0[2][2], r1[2][2];
#pragma unroll
    for (int pp = 0; pp < 2; ++pp)
#pragma unroll
      for (int i = 0; i < 2; ++i) {
        u32 s0w = hi ? w0[2 * pp][i] : w0[2 * pp + 1][i];
        r0[pp][i] = (u32)__shfl_xor((int)s0w, 32);
        u32 s1w = hi ? w1[2 * pp][i] : w1[2 * pp + 1][i];
        r1[pp][i] = (u32)__shfl_xor((int)s1w, 32);
      }
    // PV: A-frag[ks] = P[q][k=16ks+8hi+e]
#pragma unroll
    for (int ks = 0; ks < 4; ++ks) {
      const int pp = ks & 1;
      u32 a0, a1, a2, a3;
      if (ks < 2) {
        a0 = hi ? r0[pp][0] : w0[2 * pp][0];
        a1 = hi ? r0[pp][1] : w0[2 * pp][1];
        a2 = hi ? w0[2 * pp + 1][0] : r0[pp][0];
        a3 = hi ? w0[2 * pp + 1][1] : r0[pp][1];
      } else {
        a0 = hi ? r1[pp][0] : w1[2 * pp][0];
        a1 = hi ? r1[pp][1] : w1[2 * pp][1];
        a2 = hi ? w1[2 * pp + 1][0] : r1[pp][0];
        a3 = hi ? w1[2 * pp + 1][1] : r1[pp][1];
      }
      i32x4 av = {(int)a0, (int)a1, (int)a2, (int)a3};
      bf16x8 pa = __builtin_bit_cast(bf16x8, av);
      bf16x8 vA = (ks == 0) ? vf00 : (ks == 1) ? vf01 : (ks == 2) ? vf02 : vf03;
      bf16x8 vB = (ks == 0) ? vf10 : (ks == 1) ? vf11 : (ks == 2) ? vf12 : vf13;
      oacc0 = __builtin_amdgcn_mfma_f32_32x32x16_bf16(pa, vA, oacc0, 0, 0, 0);
      oacc1 = __builtin_amdgcn_mfma_f32_32x32x16_bf16(pa, vB, oacc1, 0, 0, 0);
    }
    kb0 += 64 * 320; kb1 += 64 * 320; vb0 += 64; vb1 += 64; m2p += 64;
  }

  // split-K reduction: waves 1-3 export partials; wave 0 sums.
  if (w > 0) {
#pragma unroll
    for (int r = 0; r < 16; ++r) {
      part[w - 1][0][r][lane] = oacc0[r];
      part[w - 1][1][r][lane] = oacc1[r];
    }
  }
  __syncthreads();
  if (w == 0) {
#pragma unroll
    for (int ww = 0; ww < 3; ++ww)
#pragma unroll
      for (int r = 0; r < 16; ++r) {
        oacc0[r] += part[ww][0][r][lane];
        oacc1[r] += part[ww][1][r][lane];
      }

    // epilogue: L sits in oacc1 col 15 (d=47 ones row); normalize and store
#pragma unroll
    for (int r = 0; r < 16; ++r) {
      float L = __shfl(oacc1[r], hi * 32 + 15);
      float linv = 1.0f / L;
      const int row = q0 + (r & 3) + 8 * (r >> 2) + 4 * hi;
      u16* orow = Ob + (size_t)(b * NSEQ + row) * 320 + h * 40;
      orow[l31] = f2bf(oacc0[r] * linv);
      if (l31 < 8) orow[32 + l31] = f2bf(oacc1[r] * linv);
    }
  }
}

// ---------------------------------------------------------------- launcher
extern "C" void kernel_launch(void* const* d_in, const int* in_sizes, int n_in,
                              void* d_out, int out_size, void* d_ws, size_t ws_size,
                              hipStream_t stream) {
  const float* x     = (const float*)d_in[0];
  const float* ctx   = (const float*)d_in[1];
  const float* mask1 = (const float*)d_in[2];
  const float* mask2 = (const float*)d_in[3];
  const float* Wq    = (const float*)d_in[4];
  const float* Wk    = (const float*)d_in[5];
  const float* Wv    = (const float*)d_in[6];
  const float* Wo    = (const float*)d_in[7];
  const float* bo    = (const float*)d_in[8];
  unsigned char* ws  = (unsigned char*)d_ws;
  float* outp        = (float*)d_out;

  prep_kernel<<<2048, 256, 0, stream>>>(x, ctx, mask1, mask2, Wq, Wk, Wv, Wo, ws);
  gemm_all<<<dim3(480, 3), 256, 0, stream>>>(ws, nullptr, nullptr, 0);
  attn_kernel<<<1536, 256, 0, stream>>>(ws);
  gemm_all<<<dim3(480, 1), 256, 0, stream>>>(ws, bo, outp, 1);
}

// Round 6
// 226.395 us; speedup vs baseline: 1.8039x; 1.8039x over previous
//
#include <hip/hip_runtime.h>
#include <hip/hip_bf16.h>
#include <stdint.h>

typedef unsigned short u16;
typedef unsigned int u32;
typedef short bf16x8 __attribute__((ext_vector_type(8)));
typedef float f32x4 __attribute__((ext_vector_type(4)));
typedef float f32x16 __attribute__((ext_vector_type(16)));
typedef unsigned short u16x4 __attribute__((ext_vector_type(4)));
typedef int i32x4 __attribute__((ext_vector_type(4)));

#define NSEQ   3072
#define QSCALE 0.158113883008418966599446f

// ws layout (bytes)
#define OFF_XB   ((size_t)0)          // x bf16 [6144][320]
#define OFF_CB   ((size_t)3932160)    // context bf16 [6144][320]
#define OFF_WT   ((size_t)7864320)    // 4x Wt bf16 [320][320] q,k,v,o
#define OFF_QG   ((size_t)8683520)    // Q bf16 [6144][320] (scale folded)
#define OFF_KG   ((size_t)12615680)   // K bf16 [6144][320]
#define OFF_VT   ((size_t)16547840)   // V^T bf16 [16][48][3072] (40..46 zero, 47 ones)
#define OFF_OB   ((size_t)21266432)   // attn out bf16 [6144][320]
#define OFF_M1   ((size_t)25198592)   // m1i bf16 [2][3072]: 1.0 if masked else 0
#define OFF_M2   ((size_t)25210880)   // m2n bf16 [2][3072]: -1e30 if masked else 0

__device__ __forceinline__ u16 f2bf(float x) {
  __hip_bfloat16 h = __float2bfloat16(x);
  return __builtin_bit_cast(unsigned short, h);
}
__device__ __forceinline__ u32 pk(float lo, float hif) {
  return (u32)f2bf(lo) | ((u32)f2bf(hif) << 16);
}
__device__ __forceinline__ void lds_cp16(const void* g, void* l) {
  __builtin_amdgcn_global_load_lds((const __attribute__((address_space(1))) void*)g,
                                   (__attribute__((address_space(3))) void*)l, 16, 0, 0);
}

// ---------------------------------------------------------------- prep
__global__ void prep_kernel(const float* __restrict__ x, const float* __restrict__ ctx,
                            const float* __restrict__ mask1, const float* __restrict__ mask2,
                            const float* __restrict__ Wq, const float* __restrict__ Wk,
                            const float* __restrict__ Wv, const float* __restrict__ Wo,
                            unsigned char* __restrict__ ws) {
  u16* xb = (u16*)(ws + OFF_XB);
  u16* cb = (u16*)(ws + OFF_CB);
  const int T0 = 491520;            // x float4 tasks
  const int T1 = T0 + 491520;       // ctx
  const int T2 = T1 + 102400;       // W transpose (4 * 25600)
  const int T3 = T2 + 1536;         // m1i (4 u16/task)
  const int T4 = T3 + 1536;         // m2n
  const int T5 = T4 + 49152;        // V^T pad rows (8 bf16/task)
  const int stride = gridDim.x * blockDim.x;
  for (int i = blockIdx.x * blockDim.x + threadIdx.x; i < T5; i += stride) {
    if (i < T1) {
      const float* src = (i < T0) ? x : ctx;
      u16* dst = (i < T0) ? xb : cb;
      int j = (i < T0) ? i : i - T0;
      float4 v = ((const float4*)src)[j];
      u16x4 o;
      o[0] = f2bf(v.x); o[1] = f2bf(v.y); o[2] = f2bf(v.z); o[3] = f2bf(v.w);
      *(u16x4*)(dst + (size_t)j * 4) = o;
    } else if (i < T2) {
      int j = i - T1;
      int m = j / 25600, rr = j % 25600;
      const float* W = (m == 0) ? Wq : (m == 1) ? Wk : (m == 2) ? Wv : Wo;
      u16* Wt = (u16*)(ws + OFF_WT + (size_t)m * 204800);
      int base = rr * 4, d = base / 320, k = base % 320;
      u16x4 o;
#pragma unroll
      for (int t = 0; t < 4; ++t) o[t] = f2bf(W[(size_t)(k + t) * 320 + d]);
      *(u16x4*)(Wt + (size_t)d * 320 + k) = o;
    } else if (i < T4) {
      bool isM1 = i < T3;
      int j = isM1 ? (i - T2) : (i - T3);
      const float* msk = isM1 ? mask1 : mask2;
      u16* dst = (u16*)(ws + (isM1 ? OFF_M1 : OFF_M2));
      int base = j * 4, b = base / 3072, r0 = base % 3072;
      u16x4 o;
#pragma unroll
      for (int t = 0; t < 4; ++t) {
        int rr = r0 + t, ih = rr / 48, iw = rr % 48;
        float mv = msk[(size_t)b * 196608 + ih * 3072 + iw * 8];
        bool on = mv >= 0.5f;
        o[t] = isM1 ? f2bf(on ? 1.0f : 0.0f) : f2bf(on ? -1e30f : 0.0f);
      }
      *(u16x4*)(dst + base) = o;
    } else {
      int j = i - T4;
      int idx8 = j * 8;
      int bh = idx8 / 24576, rem = idx8 % 24576;
      int pr = rem / 3072, c = rem % 3072;
      u16* Vt = (u16*)(ws + OFF_VT);
      u32 fill = (pr == 7) ? 0x3F803F80u : 0u;  // row 47 = ones (softmax denom via MFMA)
      i32x4 z = {(int)fill, (int)fill, (int)fill, (int)fill};
      *(i32x4*)(Vt + (size_t)(bh * 48 + 40 + pr) * 3072 + c) = z;
    }
  }
}

// ---------------------------------------------------------------- GEMMs (merged)
// mode 0: Q = xb @ WqT^T (scaled)   mode 1: K = cb @ WkT^T
// mode 2: V^T = WvT @ cb^T          mode 3: out = Ob @ WoT^T + bo
__global__ __launch_bounds__(256) void gemm_all(unsigned char* __restrict__ ws,
                                                const float* __restrict__ bo,
                                                float* __restrict__ outf, int phase) {
  const u16* xb = (const u16*)(ws + OFF_XB);
  const u16* cb = (const u16*)(ws + OFF_CB);
  const int mode = phase ? 3 : (int)blockIdx.y;
  const u16* Ap; const u16* Bp;
  int bx = blockIdx.x;
  int mt, nt;
  if (mode == 0)      { Ap = xb; Bp = (const u16*)(ws + OFF_WT);            mt = bx / 5; nt = bx % 5; }
  else if (mode == 1) { Ap = cb; Bp = (const u16*)(ws + OFF_WT + 204800);   mt = bx / 5; nt = bx % 5; }
  else if (mode == 2) { Ap = (const u16*)(ws + OFF_WT + 2 * 204800); Bp = cb; mt = bx % 5; nt = bx / 5; }
  else                { Ap = (const u16*)(ws + OFF_OB); Bp = (const u16*)(ws + OFF_WT + 3 * 204800); mt = bx / 5; nt = bx % 5; }
  const int m0 = mt * 64, n0 = nt * 64;

  __shared__ u16 Als[64 * 32];
  __shared__ u16 Bls[64 * 32];

  const int tid = threadIdx.x;
  const int lane = tid & 63, w = tid >> 6;
  const int li = lane & 15, g = lane >> 4;

  f32x4 acc[4] = {};

  const int srow = tid >> 2, sslot = tid & 3;
  const int sgch = (sslot - ((srow >> 1) & 3)) & 3;
  const u16* aSrc = Ap + (size_t)(m0 + srow) * 320 + sgch * 8;
  const u16* bSrc = Bp + (size_t)(n0 + srow) * 320 + sgch * 8;

  const int arow = w * 16 + li;
  const int aoff = arow * 32 + (((g + ((arow >> 1) & 3)) & 3) * 8);

  for (int kt = 0; kt < 10; ++kt) {
    __syncthreads();
    lds_cp16(aSrc + kt * 32, (char*)Als + tid * 16);
    lds_cp16(bSrc + kt * 32, (char*)Bls + tid * 16);
    __syncthreads();
    bf16x8 af = *(const bf16x8*)(Als + aoff);
#pragma unroll
    for (int ct = 0; ct < 4; ++ct) {
      int brow = ct * 16 + li;
      bf16x8 bv = *(const bf16x8*)(Bls + brow * 32 + (((g + ((brow >> 1) & 3)) & 3) * 8));
      acc[ct] = __builtin_amdgcn_mfma_f32_16x16x32_bf16(af, bv, acc[ct], 0, 0, 0);
    }
  }

  const int erow = w * 16 + g * 4;
  if (mode == 0 || mode == 1) {
    u16* Og = (u16*)(ws + (mode == 0 ? OFF_QG : OFF_KG));
#pragma unroll
    for (int ct = 0; ct < 4; ++ct)
#pragma unroll
      for (int r = 0; r < 4; ++r) {
        float v = acc[ct][r];
        if (mode == 0) v *= QSCALE;
        Og[(size_t)(m0 + erow + r) * 320 + n0 + ct * 16 + li] = f2bf(v);
      }
  } else if (mode == 2) {
    u16* Vt = (u16*)(ws + OFF_VT);
#pragma unroll
    for (int ct = 0; ct < 4; ++ct)
#pragma unroll
      for (int r = 0; r < 4; ++r) {
        int d = m0 + erow + r;
        int h = d / 40, dd = d % 40;
        int n = n0 + ct * 16 + li;
        int b = (n >= 3072) ? 1 : 0;
        int nin = n - b * 3072;
        int bh = b * 8 + h;
        Vt[(size_t)(bh * 48 + dd) * 3072 + nin] = f2bf(acc[ct][r]);
      }
  } else {
#pragma unroll
    for (int ct = 0; ct < 4; ++ct) {
      float bias = bo[n0 + ct * 16 + li];
#pragma unroll
      for (int r = 0; r < 4; ++r)
        outf[(size_t)(m0 + erow + r) * 320 + n0 + ct * 16 + li] = acc[ct][r] + bias;
    }
  }
}

// ---------------------------------------------------------------- attention
// Block = one (bh, qs) pair, 4 waves; wave w handles keys [w*768, w*768+768)
// (split-K is exactly additive: no online max, partial O/L just sum).
// Swapped QK^T (A=K, B=Q); mask folded into contraction pad dim; denominator
// via ones-row 47 of V^T (oacc1 col 15). Waves 1-3 dump partials to LDS,
// wave 0 reduces + normalizes + writes.
// NOTE: launch_bounds (256,4): round-4's (256,6) capped VGPR at ~85 and the
// compiler spilled both f32x16 accumulators -> 848 MB/dispatch scratch traffic.
__global__ __launch_bounds__(256, 4) void attn_kernel(unsigned char* __restrict__ ws) {
  const u16* Qg  = (const u16*)(ws + OFF_QG);
  const u16* Kg  = (const u16*)(ws + OFF_KG);
  const u16* Vt  = (const u16*)(ws + OFF_VT);
  const u16* m1i = (const u16*)(ws + OFF_M1);
  const u16* m2n = (const u16*)(ws + OFF_M2);
  u16* Ob = (u16*)(ws + OFF_OB);

  __shared__ float part[3][2][16][64];   // [wave-1][acc][reg][lane]

  const int tid = threadIdx.x;
  const int w = tid >> 6;                 // wave in block, 0..3
  const int lane = tid & 63;
  const int l31 = lane & 31, hi = lane >> 5;

  // XCD-bijective swizzle: 1536 blocks = 8 XCD * 192; physical p -> logical
  // so each XCD hosts 2 consecutive bh (its L2 keeps their K/V resident).
  const int p = blockIdx.x;
  const int logical = (p & 7) * 192 + (p >> 3);
  const int bh = logical / 96, qs = logical % 96;
  const int b = bh >> 3, h = bh & 7;
  const int q0 = qs * 32;

  // Q B-fragments (col = q = l31, k-chunk = 2t + hi), chunk 5 = m1 indicator
  const u16* qrow = Qg + (size_t)(b * NSEQ + q0 + l31) * 320 + h * 40;
  bf16x8 qf0 = *(const bf16x8*)(qrow + hi * 8);
  bf16x8 qf1 = *(const bf16x8*)(qrow + 16 + hi * 8);
  bf16x8 qf2;
  {
    i32x4 real = *(const i32x4*)(qrow + 32);
    u16 m1v = m1i[b * NSEQ + q0 + l31];
    i32x4 mskv = {(int)(u32)m1v, 0, 0, 0};
    i32x4 sel = hi ? mskv : real;
    qf2 = __builtin_bit_cast(bf16x8, sel);
  }

  const int k0base = w * 768;
  const u16* kb0 = Kg + (size_t)(b * NSEQ + k0base + l31) * 320 + h * 40 + hi * 8;
  const u16* kb1 = kb0 + 32 * 320;
  const u16* vb0 = Vt + ((size_t)(bh * 48) + l31) * 3072 + k0base + hi * 8;
  const u16* vb1 = vb0 + 32 * 3072;
  const u16* m2p = m2n + b * NSEQ + k0base + l31;

  f32x16 oacc0 = {}, oacc1 = {};

#pragma unroll 2
  for (int kt = 0; kt < 12; ++kt) {
    // K A-frags (row = key = l31 (+32), k-chunk = 2t + hi)
    bf16x8 ka00 = *(const bf16x8*)(kb0);
    bf16x8 ka01 = *(const bf16x8*)(kb0 + 16);
    bf16x8 ka02 = *(const bf16x8*)(kb0 + 32);
    bf16x8 ka10 = *(const bf16x8*)(kb1);
    bf16x8 ka11 = *(const bf16x8*)(kb1 + 16);
    bf16x8 ka12 = *(const bf16x8*)(kb1 + 32);
    u16 m2v0 = m2p[0], m2v1 = m2p[32];
    // V B-frags (col = d = l31 (+32), k = ks*16 + 8*hi + e)
    bf16x8 vf00 = *(const bf16x8*)(vb0);
    bf16x8 vf01 = *(const bf16x8*)(vb0 + 16);
    bf16x8 vf02 = *(const bf16x8*)(vb0 + 32);
    bf16x8 vf03 = *(const bf16x8*)(vb0 + 48);
    bf16x8 vf10 = *(const bf16x8*)(vb1);
    bf16x8 vf11 = *(const bf16x8*)(vb1 + 16);
    bf16x8 vf12 = *(const bf16x8*)(vb1 + 32);
    bf16x8 vf13 = *(const bf16x8*)(vb1 + 48);

    // hi=1 lanes: replace chunk-5 with mask row (-1e30 if m2)
    {
      i32x4 mv0 = {(int)(u32)m2v0, 0, 0, 0};
      i32x4 mv1 = {(int)(u32)m2v1, 0, 0, 0};
      ka02 = hi ? __builtin_bit_cast(bf16x8, mv0) : ka02;
      ka12 = hi ? __builtin_bit_cast(bf16x8, mv1) : ka12;
    }

    f32x16 s0 = {}, s1 = {};
    s0 = __builtin_amdgcn_mfma_f32_32x32x16_bf16(ka00, qf0, s0, 0, 0, 0);
    s0 = __builtin_amdgcn_mfma_f32_32x32x16_bf16(ka01, qf1, s0, 0, 0, 0);
    s0 = __builtin_amdgcn_mfma_f32_32x32x16_bf16(ka02, qf2, s0, 0, 0, 0);
    s1 = __builtin_amdgcn_mfma_f32_32x32x16_bf16(ka10, qf0, s1, 0, 0, 0);
    s1 = __builtin_amdgcn_mfma_f32_32x32x16_bf16(ka11, qf1, s1, 0, 0, 0);
    s1 = __builtin_amdgcn_mfma_f32_32x32x16_bf16(ka12, qf2, s1, 0, 0, 0);

    // exp (no max subtraction: |S| bounded, masked -> exact 0) + bf16 pack
    u32 w0[4][2], w1[4][2];
#pragma unroll
    for (int t = 0; t < 4; ++t) {
      w0[t][0] = pk(__expf(s0[4 * t]),     __expf(s0[4 * t + 1]));
      w0[t][1] = pk(__expf(s0[4 * t + 2]), __expf(s0[4 * t + 3]));
      w1[t][0] = pk(__expf(s1[4 * t]),     __expf(s1[4 * t + 1]));
      w1[t][1] = pk(__expf(s1[4 * t + 2]), __expf(s1[4 * t + 3]));
    }
    // cross-half exchange (muxed so each lane sends what its partner needs)
    u32 r0[2][2], r1[2][2];
#pragma unroll
    for (int pp = 0; pp < 2; ++pp)
#pragma unroll
      for (int i = 0; i < 2; ++i) {
        u32 s0w = hi ? w0[2 * pp][i] : w0[2 * pp + 1][i];
        r0[pp][i] = (u32)__shfl_xor((int)s0w, 32);
        u32 s1w = hi ? w1[2 * pp][i] : w1[2 * pp + 1][i];
        r1[pp][i] = (u32)__shfl_xor((int)s1w, 32);
      }
    // PV: A-frag[ks] = P[q][k=16ks+8hi+e]
#pragma unroll
    for (int ks = 0; ks < 4; ++ks) {
      const int pp = ks & 1;
      u32 a0, a1, a2, a3;
      if (ks < 2) {
        a0 = hi ? r0[pp][0] : w0[2 * pp][0];
        a1 = hi ? r0[pp][1] : w0[2 * pp][1];
        a2 = hi ? w0[2 * pp + 1][0] : r0[pp][0];
        a3 = hi ? w0[2 * pp + 1][1] : r0[pp][1];
      } else {
        a0 = hi ? r1[pp][0] : w1[2 * pp][0];
        a1 = hi ? r1[pp][1] : w1[2 * pp][1];
        a2 = hi ? w1[2 * pp + 1][0] : r1[pp][0];
        a3 = hi ? w1[2 * pp + 1][1] : r1[pp][1];
      }
      i32x4 av = {(int)a0, (int)a1, (int)a2, (int)a3};
      bf16x8 pa = __builtin_bit_cast(bf16x8, av);
      bf16x8 vA = (ks == 0) ? vf00 : (ks == 1) ? vf01 : (ks == 2) ? vf02 : vf03;
      bf16x8 vB = (ks == 0) ? vf10 : (ks == 1) ? vf11 : (ks == 2) ? vf13 : vf13;
      if (ks == 2) vB = vf12;
      oacc0 = __builtin_amdgcn_mfma_f32_32x32x16_bf16(pa, vA, oacc0, 0, 0, 0);
      oacc1 = __builtin_amdgcn_mfma_f32_32x32x16_bf16(pa, vB, oacc1, 0, 0, 0);
    }
    kb0 += 64 * 320; kb1 += 64 * 320; vb0 += 64; vb1 += 64; m2p += 64;
  }

  // split-K reduction: waves 1-3 export partials; wave 0 sums.
  if (w > 0) {
#pragma unroll
    for (int r = 0; r < 16; ++r) {
      part[w - 1][0][r][lane] = oacc0[r];
      part[w - 1][1][r][lane] = oacc1[r];
    }
  }
  __syncthreads();
  if (w == 0) {
#pragma unroll
    for (int ww = 0; ww < 3; ++ww)
#pragma unroll
      for (int r = 0; r < 16; ++r) {
        oacc0[r] += part[ww][0][r][lane];
        oacc1[r] += part[ww][1][r][lane];
      }

    // epilogue: L sits in oacc1 col 15 (d=47 ones row); normalize and store
#pragma unroll
    for (int r = 0; r < 16; ++r) {
      float L = __shfl(oacc1[r], hi * 32 + 15);
      float linv = 1.0f / L;
      const int row = q0 + (r & 3) + 8 * (r >> 2) + 4 * hi;
      u16* orow = Ob + (size_t)(b * NSEQ + row) * 320 + h * 40;
      orow[l31] = f2bf(oacc0[r] * linv);
      if (l31 < 8) orow[32 + l31] = f2bf(oacc1[r] * linv);
    }
  }
}

// ---------------------------------------------------------------- launcher
extern "C" void kernel_launch(void* const* d_in, const int* in_sizes, int n_in,
                              void* d_out, int out_size, void* d_ws, size_t ws_size,
                              hipStream_t stream) {
  const float* x     = (const float*)d_in[0];
  const float* ctx   = (const float*)d_in[1];
  const float* mask1 = (const float*)d_in[2];
  const float* mask2 = (const float*)d_in[3];
  const float* Wq    = (const float*)d_in[4];
  const float* Wk    = (const float*)d_in[5];
  const float* Wv    = (const float*)d_in[6];
  const float* Wo    = (const float*)d_in[7];
  const float* bo    = (const float*)d_in[8];
  unsigned char* ws  = (unsigned char*)d_ws;
  float* outp        = (float*)d_out;

  prep_kernel<<<2048, 256, 0, stream>>>(x, ctx, mask1, mask2, Wq, Wk, Wv, Wo, ws);
  gemm_all<<<dim3(480, 3), 256, 0, stream>>>(ws, nullptr, nullptr, 0);
  attn_kernel<<<1536, 256, 0, stream>>>(ws);
  gemm_all<<<dim3(480, 1), 256, 0, stream>>>(ws, bo, outp, 1);
}

// Round 8
// 167.775 us; speedup vs baseline: 2.4342x; 1.3494x over previous
//
#include <hip/hip_runtime.h>
#include <hip/hip_bf16.h>
#include <stdint.h>

typedef unsigned short u16;
typedef unsigned int u32;
typedef short bf16x8 __attribute__((ext_vector_type(8)));
typedef float f32x4 __attribute__((ext_vector_type(4)));
typedef float f32x16 __attribute__((ext_vector_type(16)));
typedef unsigned short u16x4 __attribute__((ext_vector_type(4)));
typedef int i32x4 __attribute__((ext_vector_type(4)));

#define NSEQ   3072
#define QSCALE 0.158113883008418966599446f

// ws layout (bytes)
#define OFF_XB   ((size_t)0)          // x bf16 [6144][320]
#define OFF_CB   ((size_t)3932160)    // context bf16 [6144][320]
#define OFF_WT   ((size_t)7864320)    // 4x Wt bf16 [320][320] q,k,v,o
#define OFF_QG   ((size_t)8683520)    // Q bf16 [6144][320] (scale folded)
#define OFF_KG   ((size_t)12615680)   // K bf16 [6144][320]
#define OFF_VT   ((size_t)16547840)   // V^T bf16 [16][48][3072] (40..46 zero, 47 ones)
#define OFF_OB   ((size_t)21266432)   // attn out bf16 [6144][320]
#define OFF_M1   ((size_t)25198592)   // m1i bf16 [2][3072]: 1.0 if masked else 0
#define OFF_M2   ((size_t)25210880)   // m2n bf16 [2][3072]: -1e30 if masked else 0

__device__ __forceinline__ u16 f2bf(float x) {
  __hip_bfloat16 h = __float2bfloat16(x);
  return __builtin_bit_cast(unsigned short, h);
}
__device__ __forceinline__ u32 pk(float lo, float hif) {
  return (u32)f2bf(lo) | ((u32)f2bf(hif) << 16);
}
__device__ __forceinline__ void lds_cp16(const void* g, void* l) {
  __builtin_amdgcn_global_load_lds((const __attribute__((address_space(1))) void*)g,
                                   (__attribute__((address_space(3))) void*)l, 16, 0, 0);
}

// ---------------------------------------------------------------- prep
__global__ void prep_kernel(const float* __restrict__ x, const float* __restrict__ ctx,
                            const float* __restrict__ mask1, const float* __restrict__ mask2,
                            const float* __restrict__ Wq, const float* __restrict__ Wk,
                            const float* __restrict__ Wv, const float* __restrict__ Wo,
                            unsigned char* __restrict__ ws) {
  u16* xb = (u16*)(ws + OFF_XB);
  u16* cb = (u16*)(ws + OFF_CB);
  const int T0 = 491520;            // x float4 tasks
  const int T1 = T0 + 491520;       // ctx
  const int T2 = T1 + 102400;       // W transpose (4 * 25600)
  const int T3 = T2 + 1536;         // m1i (4 u16/task)
  const int T4 = T3 + 1536;         // m2n
  const int T5 = T4 + 49152;        // V^T pad rows (8 bf16/task)
  const int stride = gridDim.x * blockDim.x;
  for (int i = blockIdx.x * blockDim.x + threadIdx.x; i < T5; i += stride) {
    if (i < T1) {
      const float* src = (i < T0) ? x : ctx;
      u16* dst = (i < T0) ? xb : cb;
      int j = (i < T0) ? i : i - T0;
      float4 v = ((const float4*)src)[j];
      u16x4 o;
      o[0] = f2bf(v.x); o[1] = f2bf(v.y); o[2] = f2bf(v.z); o[3] = f2bf(v.w);
      *(u16x4*)(dst + (size_t)j * 4) = o;
    } else if (i < T2) {
      int j = i - T1;
      int m = j / 25600, rr = j % 25600;
      const float* W = (m == 0) ? Wq : (m == 1) ? Wk : (m == 2) ? Wv : Wo;
      u16* Wt = (u16*)(ws + OFF_WT + (size_t)m * 204800);
      int base = rr * 4, d = base / 320, k = base % 320;
      u16x4 o;
#pragma unroll
      for (int t = 0; t < 4; ++t) o[t] = f2bf(W[(size_t)(k + t) * 320 + d]);
      *(u16x4*)(Wt + (size_t)d * 320 + k) = o;
    } else if (i < T4) {
      bool isM1 = i < T3;
      int j = isM1 ? (i - T2) : (i - T3);
      const float* msk = isM1 ? mask1 : mask2;
      u16* dst = (u16*)(ws + (isM1 ? OFF_M1 : OFF_M2));
      int base = j * 4, b = base / 3072, r0 = base % 3072;
      u16x4 o;
#pragma unroll
      for (int t = 0; t < 4; ++t) {
        int rr = r0 + t, ih = rr / 48, iw = rr % 48;
        float mv = msk[(size_t)b * 196608 + ih * 3072 + iw * 8];
        bool on = mv >= 0.5f;
        o[t] = isM1 ? f2bf(on ? 1.0f : 0.0f) : f2bf(on ? -1e30f : 0.0f);
      }
      *(u16x4*)(dst + base) = o;
    } else {
      int j = i - T4;
      int idx8 = j * 8;
      int bh = idx8 / 24576, rem = idx8 % 24576;
      int pr = rem / 3072, c = rem % 3072;
      u16* Vt = (u16*)(ws + OFF_VT);
      u32 fill = (pr == 7) ? 0x3F803F80u : 0u;  // row 47 = ones (softmax denom via MFMA)
      i32x4 z = {(int)fill, (int)fill, (int)fill, (int)fill};
      *(i32x4*)(Vt + (size_t)(bh * 48 + 40 + pr) * 3072 + c) = z;
    }
  }
}

// ---------------------------------------------------------------- GEMMs (merged)
// mode 0: Q = xb @ WqT^T (scaled)   mode 1: K = cb @ WkT^T
// mode 2: V^T = WvT @ cb^T          mode 3: out = Ob @ WoT^T + bo
__global__ __launch_bounds__(256) void gemm_all(unsigned char* __restrict__ ws,
                                                const float* __restrict__ bo,
                                                float* __restrict__ outf, int phase) {
  const u16* xb = (const u16*)(ws + OFF_XB);
  const u16* cb = (const u16*)(ws + OFF_CB);
  const int mode = phase ? 3 : (int)blockIdx.y;
  const u16* Ap; const u16* Bp;
  int bx = blockIdx.x;
  int mt, nt;
  if (mode == 0)      { Ap = xb; Bp = (const u16*)(ws + OFF_WT);            mt = bx / 5; nt = bx % 5; }
  else if (mode == 1) { Ap = cb; Bp = (const u16*)(ws + OFF_WT + 204800);   mt = bx / 5; nt = bx % 5; }
  else if (mode == 2) { Ap = (const u16*)(ws + OFF_WT + 2 * 204800); Bp = cb; mt = bx % 5; nt = bx / 5; }
  else                { Ap = (const u16*)(ws + OFF_OB); Bp = (const u16*)(ws + OFF_WT + 3 * 204800); mt = bx / 5; nt = bx % 5; }
  const int m0 = mt * 64, n0 = nt * 64;

  __shared__ u16 Als[64 * 32];
  __shared__ u16 Bls[64 * 32];

  const int tid = threadIdx.x;
  const int lane = tid & 63, w = tid >> 6;
  const int li = lane & 15, g = lane >> 4;

  f32x4 acc[4] = {};

  const int srow = tid >> 2, sslot = tid & 3;
  const int sgch = (sslot - ((srow >> 1) & 3)) & 3;
  const u16* aSrc = Ap + (size_t)(m0 + srow) * 320 + sgch * 8;
  const u16* bSrc = Bp + (size_t)(n0 + srow) * 320 + sgch * 8;

  const int arow = w * 16 + li;
  const int aoff = arow * 32 + (((g + ((arow >> 1) & 3)) & 3) * 8);

  for (int kt = 0; kt < 10; ++kt) {
    __syncthreads();
    lds_cp16(aSrc + kt * 32, (char*)Als + tid * 16);
    lds_cp16(bSrc + kt * 32, (char*)Bls + tid * 16);
    __syncthreads();
    bf16x8 af = *(const bf16x8*)(Als + aoff);
#pragma unroll
    for (int ct = 0; ct < 4; ++ct) {
      int brow = ct * 16 + li;
      bf16x8 bv = *(const bf16x8*)(Bls + brow * 32 + (((g + ((brow >> 1) & 3)) & 3) * 8));
      acc[ct] = __builtin_amdgcn_mfma_f32_16x16x32_bf16(af, bv, acc[ct], 0, 0, 0);
    }
  }

  const int erow = w * 16 + g * 4;
  if (mode == 0 || mode == 1) {
    u16* Og = (u16*)(ws + (mode == 0 ? OFF_QG : OFF_KG));
#pragma unroll
    for (int ct = 0; ct < 4; ++ct)
#pragma unroll
      for (int r = 0; r < 4; ++r) {
        float v = acc[ct][r];
        if (mode == 0) v *= QSCALE;
        Og[(size_t)(m0 + erow + r) * 320 + n0 + ct * 16 + li] = f2bf(v);
      }
  } else if (mode == 2) {
    u16* Vt = (u16*)(ws + OFF_VT);
#pragma unroll
    for (int ct = 0; ct < 4; ++ct)
#pragma unroll
      for (int r = 0; r < 4; ++r) {
        int d = m0 + erow + r;
        int h = d / 40, dd = d % 40;
        int n = n0 + ct * 16 + li;
        int b = (n >= 3072) ? 1 : 0;
        int nin = n - b * 3072;
        int bh = b * 8 + h;
        Vt[(size_t)(bh * 48 + dd) * 3072 + nin] = f2bf(acc[ct][r]);
      }
  } else {
#pragma unroll
    for (int ct = 0; ct < 4; ++ct) {
      float bias = bo[n0 + ct * 16 + li];
#pragma unroll
      for (int r = 0; r < 4; ++r)
        outf[(size_t)(m0 + erow + r) * 320 + n0 + ct * 16 + li] = acc[ct][r] + bias;
    }
  }
}

// ---------------------------------------------------------------- attention
// Block = 4 waves over one (bh, 64 q-rows): wave (qw, kw) = (w&1, w>>1);
// qw picks 32 q-rows, kw picks key stream [kw*1536, +1536). 24 tiles of 64
// keys per stream, K+V^T staged DENSELY into LDS via global_load_lds
// (double-buffered, issue-before-compute, one barrier/tile). XOR swizzle
// slot^=(row&7) applied via pre-swizzled SOURCE addrs (linear LDS dest) and
// swizzled ds_read offsets -> bank-balanced b128 fragment reads.
// m2 mask rides the same pipeline. Math identical to round 6 (swapped QK^T,
// mask in contraction pad, denominator via ones-row 47, split-K additive).
// LDS map (u16 idx): V tile (s,b) at (s*2+b)*3072 [48x64]; K tile (s,b) at
// 12288+(s*2+b)*4096 [64x64]; m2 strip (b,s) at 28672+b*128+s*64. 56.5 KB.
// Strip layout is [bp][s] so the 16 staging lanes are LANE-LINEAR (m104:
// global_load_lds writes base+lane*16, per-lane LDS addrs are ignored).
// V-frag rows 48..63 read past the V tile into K region: finite bf16, feeds
// only oacc1 cols 16..31 which are never stored.
__global__ __launch_bounds__(256) void attn_kernel(unsigned char* __restrict__ ws) {
  const u16* Qg  = (const u16*)(ws + OFF_QG);
  const u16* Kg  = (const u16*)(ws + OFF_KG);
  const u16* Vt  = (const u16*)(ws + OFF_VT);
  const u16* m1i = (const u16*)(ws + OFF_M1);
  const u16* m2n = (const u16*)(ws + OFF_M2);
  u16* Ob = (u16*)(ws + OFF_OB);

  __shared__ u16 S[28928];

  const int tid = threadIdx.x;
  const int w = tid >> 6;
  const int lane = tid & 63;
  const int l31 = lane & 31, hi = lane >> 5;
  const int qw = w & 1, kw = w >> 1;

  // XCD-bijective swizzle: 768 = 8 XCD * 96 -> each XCD hosts 2 bh.
  const int p = blockIdx.x;
  const int logical = (p & 7) * 96 + (p >> 3);
  const int bh = logical / 48, qs = logical % 48;
  const int b = bh >> 3, h = bh & 7;
  const int q0 = qs * 64 + qw * 32;

  // Q B-fragments (col = q = l31, k-chunk = 2t + hi), chunk 5 = m1 indicator
  const u16* qrow = Qg + (size_t)(b * NSEQ + q0 + l31) * 320 + h * 40;
  bf16x8 qf0 = *(const bf16x8*)(qrow + hi * 8);
  bf16x8 qf1 = *(const bf16x8*)(qrow + 16 + hi * 8);
  bf16x8 qf2;
  {
    i32x4 real = *(const i32x4*)(qrow + 32);
    u16 m1v = m1i[b * NSEQ + q0 + l31];
    i32x4 mskv = {(int)(u32)m1v, 0, 0, 0};
    i32x4 sel = hi ? mskv : real;
    qf2 = __builtin_bit_cast(bf16x8, sel);
  }

  // -------- staging decode: 1792 chunks/tile-pair = 7 rounds of 256 + strip
  const u16* src[7]; int dst[7], sst[7], bst[7];
#pragma unroll
  for (int r = 0; r < 7; ++r) {
    int cid = r * 256 + tid;
    int s = (cid >= 896) ? 1 : 0;
    int c2 = cid - s * 896;
    if (c2 < 384) {            // V chunk: 48 rows x 8 slots
      int row = c2 >> 3, slot = c2 & 7, kc = slot ^ (row & 7);
      src[r] = Vt + (size_t)(bh * 48 + row) * 3072 + s * 1536 + kc * 8;
      sst[r] = 64; dst[r] = s * 6144 + c2 * 8; bst[r] = 3072;
    } else {                   // K chunk: 64 rows x 8 slots (slots w/ kc>=6 unread)
      int kcid = c2 - 384, row = kcid >> 3, slot = kcid & 7, kc = slot ^ (row & 7);
      src[r] = Kg + (size_t)(b * NSEQ + s * 1536 + row) * 320 + h * 40 + kc * 8;
      sst[r] = 64 * 320; dst[r] = 12288 + s * 8192 + kcid * 8; bst[r] = 4096;
    }
  }
  const u16* srcm = m2n + b * NSEQ + (tid >> 3) * 1536 + (tid & 7) * 8;
  const int dstm = 28672 + tid * 8;   // lane-linear: strip(bp,s)=28672+bp*128+s*64

  f32x16 oacc0 = {}, oacc1 = {};

  auto STAGE = [&](int bp) {
#pragma unroll
    for (int r = 0; r < 7; ++r) {
      lds_cp16(src[r], &S[dst[r] + bp * bst[r]]);
      src[r] += sst[r];
    }
    if (tid < 16) { lds_cp16(srcm, &S[dstm + bp * 128]); srcm += 64; }
  };

  auto COMPUTE = [&](int rb) {
    const u16* Kt = &S[12288 + (kw * 2 + rb) * 4096];
    const u16* Vl = &S[(kw * 2 + rb) * 3072];
    const u16* Ms = &S[28672 + rb * 128 + kw * 64];
    u16 m2v0 = Ms[l31], m2v1 = Ms[32 + l31];
    const int x = l31 & 7;                 // (l31+32)&7 == l31&7
    const int rA0 = l31 * 64, rA1 = (l31 + 32) * 64;
    bf16x8 ka00 = *(const bf16x8*)(Kt + rA0 + ((hi ^ x) * 8));
    bf16x8 ka01 = *(const bf16x8*)(Kt + rA0 + (((2 + hi) ^ x) * 8));
    bf16x8 ka02 = *(const bf16x8*)(Kt + rA0 + (((4 + hi) ^ x) * 8));
    bf16x8 ka10 = *(const bf16x8*)(Kt + rA1 + ((hi ^ x) * 8));
    bf16x8 ka11 = *(const bf16x8*)(Kt + rA1 + (((2 + hi) ^ x) * 8));
    bf16x8 ka12 = *(const bf16x8*)(Kt + rA1 + (((4 + hi) ^ x) * 8));
    bf16x8 vf00 = *(const bf16x8*)(Vl + rA0 + ((hi ^ x) * 8));
    bf16x8 vf01 = *(const bf16x8*)(Vl + rA0 + (((2 + hi) ^ x) * 8));
    bf16x8 vf02 = *(const bf16x8*)(Vl + rA0 + (((4 + hi) ^ x) * 8));
    bf16x8 vf03 = *(const bf16x8*)(Vl + rA0 + (((6 + hi) ^ x) * 8));
    bf16x8 vf10 = *(const bf16x8*)(Vl + rA1 + ((hi ^ x) * 8));
    bf16x8 vf11 = *(const bf16x8*)(Vl + rA1 + (((2 + hi) ^ x) * 8));
    bf16x8 vf12 = *(const bf16x8*)(Vl + rA1 + (((4 + hi) ^ x) * 8));
    bf16x8 vf13 = *(const bf16x8*)(Vl + rA1 + (((6 + hi) ^ x) * 8));

    // hi=1 lanes: replace chunk-5 with mask row (-1e30 if m2)
    {
      i32x4 mv0 = {(int)(u32)m2v0, 0, 0, 0};
      i32x4 mv1 = {(int)(u32)m2v1, 0, 0, 0};
      ka02 = hi ? __builtin_bit_cast(bf16x8, mv0) : ka02;
      ka12 = hi ? __builtin_bit_cast(bf16x8, mv1) : ka12;
    }

    f32x16 s0 = {}, s1 = {};
    s0 = __builtin_amdgcn_mfma_f32_32x32x16_bf16(ka00, qf0, s0, 0, 0, 0);
    s0 = __builtin_amdgcn_mfma_f32_32x32x16_bf16(ka01, qf1, s0, 0, 0, 0);
    s0 = __builtin_amdgcn_mfma_f32_32x32x16_bf16(ka02, qf2, s0, 0, 0, 0);
    s1 = __builtin_amdgcn_mfma_f32_32x32x16_bf16(ka10, qf0, s1, 0, 0, 0);
    s1 = __builtin_amdgcn_mfma_f32_32x32x16_bf16(ka11, qf1, s1, 0, 0, 0);
    s1 = __builtin_amdgcn_mfma_f32_32x32x16_bf16(ka12, qf2, s1, 0, 0, 0);

    // exp (no max subtraction: |S| bounded, masked -> exact 0) + bf16 pack
    u32 w0[4][2], w1[4][2];
#pragma unroll
    for (int t = 0; t < 4; ++t) {
      w0[t][0] = pk(__expf(s0[4 * t]),     __expf(s0[4 * t + 1]));
      w0[t][1] = pk(__expf(s0[4 * t + 2]), __expf(s0[4 * t + 3]));
      w1[t][0] = pk(__expf(s1[4 * t]),     __expf(s1[4 * t + 1]));
      w1[t][1] = pk(__expf(s1[4 * t + 2]), __expf(s1[4 * t + 3]));
    }
    // cross-half exchange (muxed so each lane sends what its partner needs)
    u32 r0[2][2], r1[2][2];
#pragma unroll
    for (int pp = 0; pp < 2; ++pp)
#pragma unroll
      for (int i = 0; i < 2; ++i) {
        u32 s0w = hi ? w0[2 * pp][i] : w0[2 * pp + 1][i];
        r0[pp][i] = (u32)__shfl_xor((int)s0w, 32);
        u32 s1w = hi ? w1[2 * pp][i] : w1[2 * pp + 1][i];
        r1[pp][i] = (u32)__shfl_xor((int)s1w, 32);
      }
    // PV: A-frag[ks] = P[q][k=16ks+8hi+e]
#pragma unroll
    for (int ks = 0; ks < 4; ++ks) {
      const int pp = ks & 1;
      u32 a0, a1, a2, a3;
      if (ks < 2) {
        a0 = hi ? r0[pp][0] : w0[2 * pp][0];
        a1 = hi ? r0[pp][1] : w0[2 * pp][1];
        a2 = hi ? w0[2 * pp + 1][0] : r0[pp][0];
        a3 = hi ? w0[2 * pp + 1][1] : r0[pp][1];
      } else {
        a0 = hi ? r1[pp][0] : w1[2 * pp][0];
        a1 = hi ? r1[pp][1] : w1[2 * pp][1];
        a2 = hi ? w1[2 * pp + 1][0] : r1[pp][0];
        a3 = hi ? w1[2 * pp + 1][1] : r1[pp][1];
      }
      i32x4 av = {(int)a0, (int)a1, (int)a2, (int)a3};
      bf16x8 pa = __builtin_bit_cast(bf16x8, av);
      bf16x8 vA = (ks == 0) ? vf00 : (ks == 1) ? vf01 : (ks == 2) ? vf02 : vf03;
      bf16x8 vB = (ks == 0) ? vf10 : (ks == 1) ? vf11 : (ks == 2) ? vf12 : vf13;
      oacc0 = __builtin_amdgcn_mfma_f32_32x32x16_bf16(pa, vA, oacc0, 0, 0, 0);
      oacc1 = __builtin_amdgcn_mfma_f32_32x32x16_bf16(pa, vB, oacc1, 0, 0, 0);
    }
  };

  // -------- main loop: dbuf, stage-issue before compute, 1 barrier/tile
  STAGE(0);
  __syncthreads();
  for (int t = 0; t < 24; t += 2) {
    STAGE(1);                 // tile t+1 -> buf1 (flies during compute)
    COMPUTE(0);               // tile t from buf0
    __syncthreads();          // drains vmcnt: buf1 ready; buf0 free
    if (t + 2 < 24) STAGE(0); // tile t+2 -> buf0
    COMPUTE(1);               // tile t+1 from buf1
    __syncthreads();
  }

  // -------- split-K merge (kw=1 -> LDS, kw=0 sums), normalize, store
  float* PF = (float*)S;
  if (kw == 1) {
#pragma unroll
    for (int r = 0; r < 16; ++r) {
      PF[qw * 2048 + r * 64 + lane] = oacc0[r];
      PF[qw * 2048 + 1024 + r * 64 + lane] = oacc1[r];
    }
  }
  __syncthreads();
  if (kw == 0) {
#pragma unroll
    for (int r = 0; r < 16; ++r) {
      oacc0[r] += PF[qw * 2048 + r * 64 + lane];
      oacc1[r] += PF[qw * 2048 + 1024 + r * 64 + lane];
    }
    // epilogue: L sits in oacc1 col 15 (d=47 ones row); normalize and store
#pragma unroll
    for (int r = 0; r < 16; ++r) {
      float L = __shfl(oacc1[r], hi * 32 + 15);
      float linv = 1.0f / L;
      const int row = q0 + (r & 3) + 8 * (r >> 2) + 4 * hi;
      u16* orow = Ob + (size_t)(b * NSEQ + row) * 320 + h * 40;
      orow[l31] = f2bf(oacc0[r] * linv);
      if (l31 < 8) orow[32 + l31] = f2bf(oacc1[r] * linv);
    }
  }
}

// ---------------------------------------------------------------- launcher
extern "C" void kernel_launch(void* const* d_in, const int* in_sizes, int n_in,
                              void* d_out, int out_size, void* d_ws, size_t ws_size,
                              hipStream_t stream) {
  const float* x     = (const float*)d_in[0];
  const float* ctx   = (const float*)d_in[1];
  const float* mask1 = (const float*)d_in[2];
  const float* mask2 = (const float*)d_in[3];
  const float* Wq    = (const float*)d_in[4];
  const float* Wk    = (const float*)d_in[5];
  const float* Wv    = (const float*)d_in[6];
  const float* Wo    = (const float*)d_in[7];
  const float* bo    = (const float*)d_in[8];
  unsigned char* ws  = (unsigned char*)d_ws;
  float* outp        = (float*)d_out;

  prep_kernel<<<2048, 256, 0, stream>>>(x, ctx, mask1, mask2, Wq, Wk, Wv, Wo, ws);
  gemm_all<<<dim3(480, 3), 256, 0, stream>>>(ws, nullptr, nullptr, 0);
  attn_kernel<<<768, 256, 0, stream>>>(ws);
  gemm_all<<<dim3(480, 1), 256, 0, stream>>>(ws, bo, outp, 1);
}